// Round 7
// baseline (301.243 us; speedup 1.0000x reference)
//
#include <hip/hip_runtime.h>
#include <hip/hip_fp16.h>

typedef _Float16 f16x8 __attribute__((ext_vector_type(8)));
typedef float f32x4 __attribute__((ext_vector_type(4)));

// ================= bucketed CSR build (r6-proven, untouched) =================
#define BSH 9
#define BSZ 512
#define CAP 12288

__global__ __launch_bounds__(256) void passA(const int* __restrict__ ei,
                                             int* __restrict__ bcount, int E, int NB) {
  __shared__ int hist[256];
  int t = threadIdx.x;
  hist[t] = 0;
  __syncthreads();
  for (int e = blockIdx.x * 256 + t; e < E; e += gridDim.x * 256)
    atomicAdd(&hist[ei[E + e] >> BSH], 1);
  __syncthreads();
  if (t < NB && hist[t]) atomicAdd(&bcount[t], hist[t]);
}

__global__ __launch_bounds__(256) void scanB(const int* __restrict__ bcount,
                                             int* __restrict__ bstart,
                                             int* __restrict__ bfill, int NB, int E) {
  __shared__ int s[256];
  int t = threadIdx.x;
  int v = (t < NB) ? bcount[t] : 0;
  s[t] = v;
  __syncthreads();
  for (int off = 1; off < 256; off <<= 1) {
    int add = (t >= off) ? s[t - off] : 0;
    __syncthreads();
    s[t] += add;
    __syncthreads();
  }
  if (t < NB) {
    int ex = s[t] - v;
    bstart[t] = ex;
    bfill[t] = ex;
  }
  if (t == 0) bstart[NB] = E;
}

// ============ MFMA GEMM body (r6-proven) ============
template <int NC, int NWC, bool IN_F16, bool SCALE>
__device__ __forceinline__ void gemm_mfma_body(
    const void* __restrict__ Xv, const float* __restrict__ W,
    const float* __restrict__ dinv, _Float16* __restrict__ G, int nrows, int bid,
    _Float16* Bs) {
  int t = threadIdx.x;
  {
    int n = t % NC;
    int kh = (t / NC) * (NC / 2);
    constexpr int NBLK = (NC / 2) / 8;
#pragma unroll
    for (int b = 0; b < NBLK; ++b) {
      f16x8 tmp;
#pragma unroll
      for (int j = 0; j < 8; ++j)
        tmp[j] = (_Float16)W[(size_t)(kh + b * 8 + j) * NC + n];
      *(f16x8*)(&Bs[n * 136 + kh + b * 8]) = tmp;
    }
  }
  __syncthreads();

  int w = t >> 6, lane = t & 63;
  int m = lane & 15, q = lane >> 4;
  int wr = (w / NWC) * 64, wc = (w % NWC) * 64;
  int row0 = bid * ((4 / NWC) * 64);

  f32x4 acc[4][4];
#pragma unroll
  for (int rt = 0; rt < 4; ++rt)
#pragma unroll
    for (int ct = 0; ct < 4; ++ct)
#pragma unroll
      for (int qq = 0; qq < 4; ++qq) acc[rt][ct][qq] = 0.f;

#pragma unroll
  for (int kc = 0; kc < 4; ++kc) {
    int kbase = kc * 32 + q * 8;
    f16x8 af[4];
#pragma unroll
    for (int rt = 0; rt < 4; ++rt) {
      int row = row0 + wr + rt * 16 + m;
      if constexpr (IN_F16) {
        f16x8 a = {0, 0, 0, 0, 0, 0, 0, 0};
        if (row < nrows) a = *(const f16x8*)((const _Float16*)Xv + (size_t)row * 128 + kbase);
        af[rt] = a;
      } else {
        float4 x0 = {0, 0, 0, 0}, x1 = {0, 0, 0, 0};
        if (row < nrows) {
          const float* Xf = (const float*)Xv;
          x0 = *(const float4*)(Xf + (size_t)row * 128 + kbase);
          x1 = *(const float4*)(Xf + (size_t)row * 128 + kbase + 4);
        }
        f16x8 a;
        a[0] = (_Float16)x0.x; a[1] = (_Float16)x0.y;
        a[2] = (_Float16)x0.z; a[3] = (_Float16)x0.w;
        a[4] = (_Float16)x1.x; a[5] = (_Float16)x1.y;
        a[6] = (_Float16)x1.z; a[7] = (_Float16)x1.w;
        af[rt] = a;
      }
    }
    f16x8 bf[4];
#pragma unroll
    for (int ct = 0; ct < 4; ++ct) {
      int n = wc + ct * 16 + m;
      bf[ct] = *(f16x8*)(&Bs[n * 136 + kbase]);
    }
#pragma unroll
    for (int rt = 0; rt < 4; ++rt)
#pragma unroll
      for (int ct = 0; ct < 4; ++ct)
        acc[rt][ct] = __builtin_amdgcn_mfma_f32_16x16x32_f16(af[rt], bf[ct],
                                                             acc[rt][ct], 0, 0, 0);
  }
#pragma unroll
  for (int rt = 0; rt < 4; ++rt) {
#pragma unroll
    for (int r = 0; r < 4; ++r) {
      int row = row0 + wr + rt * 16 + q * 4 + r;
      if (row < nrows) {
        float d = SCALE ? dinv[row] : 1.f;
#pragma unroll
        for (int ct = 0; ct < 4; ++ct) {
          int col = wc + ct * 16 + m;
          G[(size_t)row * NC + col] = (_Float16)(acc[rt][ct][r] * d);
        }
      }
    }
  }
}

// ===== fused: gemm1 (MFMA, unscaled, fp32-in) interleaved with passB (r6-proven) =====
__global__ __launch_bounds__(256) void fused_gemm_passB(
    const float* __restrict__ X, const float* __restrict__ W1,
    _Float16* __restrict__ G, int nrows, int GB,
    const int* __restrict__ ei, int* __restrict__ bfill,
    unsigned int* __restrict__ pairs, int E, int PB) {
  __shared__ char smem[128 * 136 * 2];
  int g = blockIdx.x;
  int M2 = 2 * (GB < PB ? GB : PB);
  bool is_gemm;
  int bid;
  if (g < M2) { is_gemm = (g & 1) == 0; bid = g >> 1; }
  else        { is_gemm = (GB > PB);    bid = g - M2 + (GB < PB ? GB : PB); }
  if (is_gemm) {
    gemm_mfma_body<128, 2, false, false>(X, W1, nullptr, G, nrows, bid,
                                         (_Float16*)smem);
  } else {
    int* hist = (int*)smem;
    int* gbase = (int*)(smem + 1024);
    int t = threadIdx.x;
    hist[t] = 0;
    __syncthreads();
    int d[8], s[8], lp[8], bb[8];
    int base = bid * 2048;
#pragma unroll
    for (int u = 0; u < 8; ++u) {
      int e = base + u * 256 + t;
      if (e < E) {
        d[u] = ei[E + e];
        s[u] = ei[e];
        bb[u] = d[u] >> BSH;
        lp[u] = atomicAdd(&hist[bb[u]], 1);
      } else {
        bb[u] = -1;
      }
    }
    __syncthreads();
    if (hist[t]) gbase[t] = atomicAdd(&bfill[t], hist[t]);
    __syncthreads();
#pragma unroll
    for (int u = 0; u < 8; ++u)
      if (bb[u] >= 0)
        pairs[gbase[bb[u]] + lp[u]] =
            ((unsigned int)(d[u] & (BSZ - 1)) << 17) | (unsigned int)s[u];
  }
}

// passC: per-bucket LDS count/scan/fill (r6-proven)
__global__ __launch_bounds__(512) void passC(const unsigned int* __restrict__ pairs,
                                             const int* __restrict__ bstart,
                                             int* __restrict__ rowstart,
                                             int* __restrict__ deg,
                                             float* __restrict__ dinv,
                                             int* __restrict__ csr, int N) {
  __shared__ int hcnt[BSZ];
  __shared__ int lfill[BSZ];
  __shared__ int ss[512];
  __shared__ int lcsr[CAP];
  int b = blockIdx.x;
  int t = threadIdx.x;
  int lo = bstart[b], hi = bstart[b + 1];
  int cnt = hi - lo;
  int nbase = b << BSH;
  hcnt[t] = 0;
  __syncthreads();
  for (int k = lo + t; k < hi; k += 512)
    atomicAdd(&hcnt[(pairs[k] >> 17) & (BSZ - 1)], 1);
  __syncthreads();
  int v = hcnt[t];
  ss[t] = v;
  __syncthreads();
  for (int off = 1; off < 512; off <<= 1) {
    int add = (t >= off) ? ss[t - off] : 0;
    __syncthreads();
    ss[t] += add;
    __syncthreads();
  }
  int ex = ss[t] - v;
  lfill[t] = ex;
  int node = nbase + t;
  if (node < N) {
    rowstart[node] = lo + ex;
    deg[node] = v;
    dinv[node] = rsqrtf((float)(v + 1));
  }
  __syncthreads();
  bool fits = (cnt <= CAP);
  for (int k = lo + t; k < hi; k += 512) {
    unsigned int p = pairs[k];
    int pos = atomicAdd(&lfill[(p >> 17) & (BSZ - 1)], 1);
    int src = (int)(p & 0x1FFFFu);
    if (fits) lcsr[pos] = src;
    else      csr[lo + pos] = src;
  }
  __syncthreads();
  if (fits)
    for (int k = t; k < cnt; k += 512) csr[lo + k] = lcsr[k];
}

// ===== agg128_g2: layer-1 aggregate + layer-2 linear, fused =====
// per node i: h = relu(di*(di*G[i] + sum dinv[s]*G[s]) + b1)   [128 wide]
//             g2[i,:] = di * (h @ W2)                          [64 wide, fp16]
// One wave per node; uniform scalar loads for csr/dinv; W2 staged once per
// block (grid-stride over node groups so staging amortizes ~12x).
__global__ __launch_bounds__(256) void agg128_g2(
    const __half* __restrict__ G, const int* __restrict__ csr,
    const int* __restrict__ rowstart, const int* __restrict__ deg,
    const float* __restrict__ dinv, const float* __restrict__ b1,
    const float* __restrict__ W2, __half* __restrict__ g2, int n, int ngroups) {
  __shared__ __half2 W2s[64 * 64];   // W2s[j*64+c] = (W2[2j][c], W2[2j+1][c])
  __shared__ float2 hbuf[4][64];     // per-wave h row (fp32)
  int t = threadIdx.x;
  for (int idx = t; idx < 4096; idx += 256) {
    int j = idx >> 6, c = idx & 63;
    W2s[idx] = __floats2half2_rn(W2[(size_t)(2 * j) * 64 + c],
                                 W2[(size_t)(2 * j + 1) * 64 + c]);
  }
  __syncthreads();

  int w = t >> 6, lane = t & 63;
  const __half2* Gp = (const __half2*)G;
  for (int grp = blockIdx.x; grp < ngroups; grp += gridDim.x) {
    int wid = grp * 4 + w;
    if (wid < n) {
      int i = __builtin_amdgcn_readfirstlane(wid);
      float di = dinv[i];
      float2 g = __half22float2(Gp[(size_t)i * 64 + lane]);
      float2 a = {di * g.x, di * g.y};
      int s = rowstart[i];
      int d = deg[i];
      int k = 0;
      for (; k + 3 < d; k += 4) {
        int s0 = csr[s + k], s1 = csr[s + k + 1];
        int s2 = csr[s + k + 2], s3 = csr[s + k + 3];
        float w0 = dinv[s0], w1 = dinv[s1], w2 = dinv[s2], w3 = dinv[s3];
        float2 v0 = __half22float2(Gp[(size_t)s0 * 64 + lane]);
        float2 v1 = __half22float2(Gp[(size_t)s1 * 64 + lane]);
        float2 v2 = __half22float2(Gp[(size_t)s2 * 64 + lane]);
        float2 v3 = __half22float2(Gp[(size_t)s3 * 64 + lane]);
        a.x = fmaf(w0, v0.x, a.x); a.y = fmaf(w0, v0.y, a.y);
        a.x = fmaf(w1, v1.x, a.x); a.y = fmaf(w1, v1.y, a.y);
        a.x = fmaf(w2, v2.x, a.x); a.y = fmaf(w2, v2.y, a.y);
        a.x = fmaf(w3, v3.x, a.x); a.y = fmaf(w3, v3.y, a.y);
      }
      for (; k < d; ++k) {
        int s0 = csr[s + k];
        float w0 = dinv[s0];
        float2 v0 = __half22float2(Gp[(size_t)s0 * 64 + lane]);
        a.x = fmaf(w0, v0.x, a.x); a.y = fmaf(w0, v0.y, a.y);
      }
      float2 b = ((const float2*)b1)[lane];
      float hx = fmaxf(fmaf(di, a.x, b.x), 0.f);
      float hy = fmaxf(fmaf(di, a.y, b.y), 0.f);
      hbuf[w][lane] = make_float2(hx, hy);
      // wave-internal LDS RAW: DS ops from one wave execute in order
      float acc = 0.f;
#pragma unroll 8
      for (int j = 0; j < 64; ++j) {
        float2 h = hbuf[w][j];                       // broadcast read
        float2 wf = __half22float2(W2s[j * 64 + lane]);
        acc = fmaf(h.x, wf.x, fmaf(h.y, wf.y, acc));
      }
      g2[(size_t)i * 64 + lane] = (__half)(acc * di);
    }
  }
}

// ===== agg64: out[i] = relu(di*(G2[i] + sum G2[s]) + b2), G2 dinv-folded =====
__global__ __launch_bounds__(256) void agg64(
    const __half* __restrict__ G, const int* __restrict__ csr,
    const int* __restrict__ rowstart, const int* __restrict__ deg,
    const float* __restrict__ dinv, const float* __restrict__ bias,
    float* __restrict__ out, int n) {
  int wid = blockIdx.x * 4 + (threadIdx.x >> 6);
  if (wid >= n) return;
  int i = __builtin_amdgcn_readfirstlane(wid);
  int lane = threadIdx.x & 63;
  float a = __half2float(G[(size_t)i * 64 + lane]);
  int s = rowstart[i];
  int d = deg[i];
  int k = 0;
  for (; k + 3 < d; k += 4) {
    int s0 = csr[s + k], s1 = csr[s + k + 1];
    int s2 = csr[s + k + 2], s3 = csr[s + k + 3];
    float v0 = __half2float(G[(size_t)s0 * 64 + lane]);
    float v1 = __half2float(G[(size_t)s1 * 64 + lane]);
    float v2 = __half2float(G[(size_t)s2 * 64 + lane]);
    float v3 = __half2float(G[(size_t)s3 * 64 + lane]);
    a += (v0 + v1) + (v2 + v3);
  }
  for (; k < d; ++k) {
    int s0 = csr[s + k];
    a += __half2float(G[(size_t)s0 * 64 + lane]);
  }
  float o = fmaxf(fmaf(dinv[i], a, bias[lane]), 0.f);
  out[(size_t)i * 64 + lane] = o;
}

// ================= launch =================
extern "C" void kernel_launch(void* const* d_in, const int* in_sizes, int n_in,
                              void* d_out, int out_size, void* d_ws, size_t ws_size,
                              hipStream_t stream) {
  const float* x  = (const float*)d_in[0];
  const int*   ei = (const int*)d_in[1];
  const float* W1 = (const float*)d_in[2];
  const float* b1 = (const float*)d_in[3];
  const float* W2 = (const float*)d_in[4];
  const float* b2 = (const float*)d_in[5];
  float* out = (float*)d_out;

  const int N = in_sizes[0] / 128;
  const int E = in_sizes[1] / 2;
  const int NB = (N + BSZ - 1) >> BSH;

  char* base = (char*)d_ws;
  size_t off = 0;
  auto alloc = [&](size_t bytes) -> void* {
    void* p = base + off;
    off += (bytes + 255) & ~(size_t)255;
    return p;
  };
  int*          bcount   = (int*)alloc(256 * 4);
  int*          bstart   = (int*)alloc(260 * 4);
  int*          bfill    = (int*)alloc(256 * 4);
  int*          deg      = (int*)alloc((size_t)N * 4);
  int*          rowstart = (int*)alloc((size_t)N * 4);
  float*        dinv     = (float*)alloc((size_t)N * 4);
  int*          csr      = (int*)alloc((size_t)E * 4);
  unsigned int* pairs    = (unsigned int*)alloc((size_t)E * 4);
  __half*       g1       = (__half*)alloc((size_t)N * 128 * 2);
  __half*       g2       = (__half*)alloc((size_t)N * 64 * 2);

  hipMemsetAsync(bcount, 0, 256 * 4, stream);
  passA<<<512, 256, 0, stream>>>(ei, bcount, E, NB);
  scanB<<<1, 256, 0, stream>>>(bcount, bstart, bfill, NB, E);

  int GB = (N + 127) / 128;
  int PB = (E + 2047) / 2048;
  fused_gemm_passB<<<GB + PB, 256, 0, stream>>>(x, W1, (_Float16*)g1, N, GB, ei,
                                                bfill, pairs, E, PB);
  passC<<<NB, 512, 0, stream>>>(pairs, bstart, rowstart, deg, dinv, csr, N);

  int ngroups = (N + 3) / 4;
  agg128_g2<<<2048, 256, 0, stream>>>(g1, csr, rowstart, deg, dinv, b1, W2, g2,
                                      N, ngroups);
  agg64<<<ngroups, 256, 0, stream>>>(g2, csr, rowstart, deg, dinv, b2, out, N);
}